// Round 14
// baseline (151.835 us; speedup 1.0000x reference)
//
#include <hip/hip_runtime.h>

typedef _Float16 f16;
typedef _Float16 f16x4 __attribute__((ext_vector_type(4)));
typedef _Float16 f16x8 __attribute__((ext_vector_type(8)));
typedef float f32x4 __attribute__((ext_vector_type(4)));

// async global->LDS, 16B per lane; LDS dest = wave-uniform base + lane*16
#define LOADLDS16(gp, lp)                                                     \
  __builtin_amdgcn_global_load_lds(                                           \
      (const __attribute__((address_space(1))) void*)(gp),                    \
      (__attribute__((address_space(3))) void*)(lp), 16, 0, 0)

// ---------------------------------------------------------------------------
// Elementwise cast f32 -> f16 (both activations in one launch)
// ---------------------------------------------------------------------------
__global__ __launch_bounds__(256) void k_cast2(const float* __restrict__ a,
                                               const float* __restrict__ b,
                                               f16* __restrict__ ya,
                                               f16* __restrict__ yb) {
  int i = blockIdx.x * 256 + threadIdx.x;
  const float* x;
  f16* y;
  if (i < 1048576) {
    x = a; y = ya;
  } else {
    x = b; y = yb; i -= 1048576;
  }
  float4 v = reinterpret_cast<const float4*>(x)[i];
  f16x4 o;
  o[0] = (f16)v.x; o[1] = (f16)v.y; o[2] = (f16)v.z; o[3] = (f16)v.w;
  reinterpret_cast<f16x4*>(y)[i] = o;
}

// ---------------------------------------------------------------------------
// Cast + transpose weights: W[1024][1024] f32 -> Wt[N][K] f16  (Wt[n][k]=W[k][n])
// ---------------------------------------------------------------------------
__global__ __launch_bounds__(256) void k_castw_t(
    const float* __restrict__ w0, const float* __restrict__ w1,
    const float* __restrict__ w2, const float* __restrict__ w3,
    f16* __restrict__ o0, f16* __restrict__ o1, f16* __restrict__ o2,
    f16* __restrict__ o3) {
  const float* W;
  f16* O;
  switch (blockIdx.z) {
    case 0: W = w0; O = o0; break;
    case 1: W = w1; O = o1; break;
    case 2: W = w2; O = o2; break;
    default: W = w3; O = o3; break;
  }
  __shared__ f16 T[64][72];
  const int tid = threadIdx.x;
  const int r0 = blockIdx.y * 64, c0 = blockIdx.x * 64;
#pragma unroll
  for (int i = 0; i < 4; ++i) {
    int c = i * 256 + tid;
    int row = c >> 4, col = (c & 15) * 4;
    float4 v = *reinterpret_cast<const float4*>(W + (size_t)(r0 + row) * 1024 + c0 + col);
    T[col + 0][row] = (f16)v.x;
    T[col + 1][row] = (f16)v.y;
    T[col + 2][row] = (f16)v.z;
    T[col + 3][row] = (f16)v.w;
  }
  __syncthreads();
#pragma unroll
  for (int i = 0; i < 2; ++i) {
    int c = i * 256 + tid;
    int cc = c >> 3, ro = (c & 7) * 8;
    f16x8 v;
#pragma unroll
    for (int j = 0; j < 8; ++j) v[j] = T[cc][ro + j];
    *reinterpret_cast<f16x8*>(O + (size_t)(c0 + cc) * 1024 + r0 + ro) = v;
  }
}

// ---------------------------------------------------------------------------
// Fused QKV projection: C[4096, 3072], cols 0-1023 = Xq@Wqt, 1024-2047 =
// Xkv@Wkt, 2048-3071 = Xkv@Wvt. m97 structure: BM=BN=128, BK=64, 4 waves.
// Epilogue: planes 0,1 -> head layout [bh][s][dh]; plane 2 (V) -> TRANSPOSED
// [bh][dh][s] (f16x4 stores over consecutive s) = fused k_vtrans.
// ---------------------------------------------------------------------------
__global__ __launch_bounds__(256) void k_gemm_qkv(const f16* __restrict__ Xq,
                                                  const f16* __restrict__ Xkv,
                                                  const f16* __restrict__ Bt,
                                                  f16* __restrict__ outp) {
  __shared__ f16 As[128 * 64];  // 16 KB
  __shared__ f16 Bs[128 * 64];  // 16 KB
  const int tid = threadIdx.x;
  const int w = tid >> 6, l = tid & 63;
  const int lr = l & 15, lq = l >> 4;
  const int m0 = blockIdx.y * 128, n0 = blockIdx.x * 128;
  const f16* A = (n0 < 1024) ? Xq : Xkv;
  const int wr = (w >> 1) * 64, wc = (w & 1) * 64;
  const int K = 1024;
  f32x4 acc[4][4] = {};
  for (int kt = 0; kt < K; kt += 64) {
#pragma unroll
    for (int i = 0; i < 4; ++i) {
      int c = (i * 4 + w) * 64 + l;
      LOADLDS16(A + (size_t)(m0 + (c >> 3)) * K + kt + (c & 7) * 8,
                As + (size_t)(i * 4 + w) * 512);
      LOADLDS16(Bt + (size_t)(n0 + (c >> 3)) * K + kt + (c & 7) * 8,
                Bs + (size_t)(i * 4 + w) * 512);
    }
    __syncthreads();
#pragma unroll
    for (int kk = 0; kk < 2; ++kk) {
      f16x8 af[4], bf[4];
#pragma unroll
      for (int m = 0; m < 4; ++m)
        af[m] = *reinterpret_cast<const f16x8*>(As + (wr + m * 16 + lr) * 64 + kk * 32 + lq * 8);
#pragma unroll
      for (int n = 0; n < 4; ++n)
        bf[n] = *reinterpret_cast<const f16x8*>(Bs + (wc + n * 16 + lr) * 64 + kk * 32 + lq * 8);
#pragma unroll
      for (int m = 0; m < 4; ++m)
#pragma unroll
        for (int n = 0; n < 4; ++n)
          acc[m][n] = __builtin_amdgcn_mfma_f32_16x16x32_f16(af[m], bf[n], acc[m][n], 0, 0, 0);
    }
    __syncthreads();
  }
  const bool vplane = (n0 >= 2048);
#pragma unroll
  for (int m = 0; m < 4; ++m)
#pragma unroll
    for (int n = 0; n < 4; ++n) {
      int col = n0 + wc + n * 16 + lr;
      int row0 = m0 + wr + m * 16 + lq * 4;
      int b = row0 >> 10, s0 = row0 & 1023;
      int plane = col >> 10, cc = col & 1023;
      int h = cc >> 6, dh = cc & 63;
      if (vplane) {
        f16x4 v4;
#pragma unroll
        for (int r = 0; r < 4; ++r) v4[r] = (f16)acc[m][n][r];
        *reinterpret_cast<f16x4*>(
            outp + (size_t)2 * 4194304 +
            ((size_t)(b * 16 + h)) * 65536 + (size_t)dh * 1024 + s0) = v4;
      } else {
#pragma unroll
        for (int r = 0; r < 4; ++r)
          outp[(size_t)plane * 4194304 +
               (((size_t)(b * 16 + h)) * 1024 + s0 + r) * 64 + dh] =
              (f16)acc[m][n][r];
      }
    }
}

// ---------------------------------------------------------------------------
// Output GEMM: C[M,N] f32 = A[M,K] @ Bt[N,K]^T. BM=64, BN=128 (512 blocks).
// ---------------------------------------------------------------------------
__global__ __launch_bounds__(256) void k_gemm_o(const f16* __restrict__ A,
                                                const f16* __restrict__ Bt,
                                                float* __restrict__ out, int M,
                                                int N, int K) {
  __shared__ f16 As[64 * 64];
  __shared__ f16 Bs[128 * 64];
  const int tid = threadIdx.x;
  const int w = tid >> 6, l = tid & 63;
  const int lr = l & 15, lq = l >> 4;
  const int m0 = blockIdx.y * 64, n0 = blockIdx.x * 128;
  const int wr = (w >> 1) * 32, wc = (w & 1) * 64;
  f32x4 acc[2][4] = {};
  for (int kt = 0; kt < K; kt += 64) {
#pragma unroll
    for (int i = 0; i < 2; ++i) {
      int c = (i * 4 + w) * 64 + l;
      LOADLDS16(A + (size_t)(m0 + (c >> 3)) * K + kt + (c & 7) * 8,
                As + (size_t)(i * 4 + w) * 512);
    }
#pragma unroll
    for (int i = 0; i < 4; ++i) {
      int c = (i * 4 + w) * 64 + l;
      LOADLDS16(Bt + (size_t)(n0 + (c >> 3)) * K + kt + (c & 7) * 8,
                Bs + (size_t)(i * 4 + w) * 512);
    }
    __syncthreads();
#pragma unroll
    for (int kk = 0; kk < 2; ++kk) {
      f16x8 af[2], bf[4];
#pragma unroll
      for (int m = 0; m < 2; ++m)
        af[m] = *reinterpret_cast<const f16x8*>(As + (wr + m * 16 + lr) * 64 + kk * 32 + lq * 8);
#pragma unroll
      for (int n = 0; n < 4; ++n)
        bf[n] = *reinterpret_cast<const f16x8*>(Bs + (wc + n * 16 + lr) * 64 + kk * 32 + lq * 8);
#pragma unroll
      for (int m = 0; m < 2; ++m)
#pragma unroll
        for (int n = 0; n < 4; ++n)
          acc[m][n] = __builtin_amdgcn_mfma_f32_16x16x32_f16(af[m], bf[n], acc[m][n], 0, 0, 0);
    }
    __syncthreads();
  }
#pragma unroll
  for (int m = 0; m < 2; ++m)
#pragma unroll
    for (int n = 0; n < 4; ++n)
#pragma unroll
      for (int r = 0; r < 4; ++r) {
        int row = m0 + wr + m * 16 + lq * 4 + r;
        int col = n0 + wc + n * 16 + lr;
        out[(size_t)row * N + col] = acc[m][n][r];
      }
}

// ---------------------------------------------------------------------------
// Fused flash attention (T5: scores = QK^T + bias, no 1/sqrt scale).
// v14: BATCH-SHARING. Block = (h, qt) over ALL 4 batches: 512 threads,
// 8 waves, wave = (batch bb = w>>1, q-half qs = w&1), QBLK=32, KVBLK=32.
// Bias slice read ONCE per block (4x less bias traffic: 256 -> 64 MB total,
// the cross-variant invariant identified in round 13). K/V for 4 batches
// staged per tile (32 KB, dbuf, 64 KB LDS -> 2 blocks/CU).
// Race-free counted pipeline: body t issues stage(t+1) then bias(t+1) regs;
// computes tile t; vmcnt(2) at body END (drains stage(t+1), keeps bias
// flying) BEFORE s_barrier -> published to all waves, no cross-wave DMA race.
// Compute: swapped QK (S^T = K Q^T), defer-max, in-register P (pi-permuted
// PV fragments), per-lane rsum + deferred reduction — verified v12/v13 code
// with KVBLK=32 indices.
// ---------------------------------------------------------------------------
__global__ __launch_bounds__(512) void k_attn(const f16* __restrict__ qb,
                                              const f16* __restrict__ kb,
                                              const f16* __restrict__ vtb,
                                              const float* __restrict__ bias,
                                              f16* __restrict__ ctx) {
  const int bid = blockIdx.x;
  const int ord = (bid & 7) * 64 + (bid >> 3);  // XCD-chunked: 2 heads/XCD
  const int h = ord >> 5, qt = ord & 31;
  const int q0 = qt * 32;
  const int tid = threadIdx.x, w = tid >> 6, l = tid & 63;
  const int lr = l & 15, lq = l >> 4;
  const int bb = w >> 1, qs = w & 1;
  const int bh = bb * 16 + h;

  __shared__ f16 Kb[2][8192];  // [batch][kv=32][dh=64], granule swz g^(row&7)
  __shared__ f16 Vb[2][8192];  // [batch][dh=64][kv=32], granule swz g^(row&3)

  // Q B-fragment: Q[q = q0+qs*16+lr][dh = lq*8 (+32)]
  const f16* qp = qb + ((size_t)bh * 1024 + q0 + qs * 16 + lr) * 64 + lq * 8;
  f16x8 qf0 = *reinterpret_cast<const f16x8*>(qp);
  f16x8 qf1 = *reinterpret_cast<const f16x8*>(qp + 32);

  f32x4 O[4] = {};
  float mrun = -3.0e38f, rsum = 0.f;  // per-lane; q-row = lr

  // per-lane bias base (shared across batches; L2 dedupes the 4 copies)
  const float* bq =
      bias + ((size_t)h * 1024 + q0 + qs * 16 + lr) * 1024 + lq * 4;

  // staging: 1024 chunks/tile (4 batches x 256), 2 rounds x 512 threads.
  auto stage = [&](int t, int nxt) {
#pragma unroll
    for (int i = 0; i < 2; ++i) {
      int c = i * 512 + tid;            // 0..1023
      int bb2 = c >> 8, cc = c & 255;   // batch, chunk-in-batch
      int bh2 = bb2 * 16 + h;
      int kr = cc >> 3, kg = (cc & 7) ^ (kr & 7);
      LOADLDS16(kb + (size_t)bh2 * 65536 + (size_t)(t * 32 + kr) * 64 + kg * 8,
                &Kb[nxt][(size_t)(i * 512 + w * 64) * 8]);
      int vr = cc >> 2, vg = (cc & 3) ^ (vr & 3);
      LOADLDS16(vtb + (size_t)bh2 * 65536 + (size_t)vr * 1024 + t * 32 + vg * 8,
                &Vb[nxt][(size_t)(i * 512 + w * 64) * 8]);
    }
  };

  // ---- prologue: stage tile 0, bias tile 0; drain stage; publish ----
  stage(0, 0);
  f32x4 bA[2], bB[2];
#pragma unroll
  for (int c = 0; c < 2; ++c) bA[c] = *reinterpret_cast<const f32x4*>(bq + c * 16);
  asm volatile("s_waitcnt vmcnt(2)" ::: "memory");  // drain stage(0), keep bias
  __builtin_amdgcn_sched_barrier(0);
  __builtin_amdgcn_s_barrier();

  auto body = [&](int t, f32x4 (&bc)[2], f32x4 (&bn)[2]) {
    const int cur = t & 1;
    // ---- issue next tile: stage DMAs first, then bias reg loads ----
    if (t < 31) {
      stage(t + 1, cur ^ 1);
      __builtin_amdgcn_sched_barrier(0);
#pragma unroll
      for (int c = 0; c < 2; ++c)
        bn[c] = *reinterpret_cast<const f32x4*>(bq + (t + 1) * 32 + c * 16);
    }
    __builtin_amdgcn_sched_barrier(0);

    // ---- S^T = K Q^T  (rows kv = c*16+lq*4+r, cols q) ----
    const f16* Kcb = &Kb[cur][bb * 2048];
    f32x4 S[2] = {};
    __builtin_amdgcn_s_setprio(1);
#pragma unroll
    for (int c = 0; c < 2; ++c) {
      int row = c * 16 + lr;
      const f16* kbp = Kcb + row * 64;
      f16x8 kf0 = *reinterpret_cast<const f16x8*>(kbp + ((lq ^ (row & 7)) * 8));
      f16x8 kf1 = *reinterpret_cast<const f16x8*>(kbp + (((4 + lq) ^ (row & 7)) * 8));
      S[c] = __builtin_amdgcn_mfma_f32_16x16x32_f16(kf0, qf0, S[c], 0, 0, 0);
      S[c] = __builtin_amdgcn_mfma_f32_16x16x32_f16(kf1, qf1, S[c], 0, 0, 0);
    }
    __builtin_amdgcn_s_setprio(0);

    // ---- + bias (registers, loaded LAST body -> full-body cover) ----
#pragma unroll
    for (int c = 0; c < 2; ++c)
#pragma unroll
      for (int r = 0; r < 4; ++r) S[c][r] += bc[c][r];

    // ---- defer-max (T13) ----
    float tmax = fmaxf(fmaxf(fmaxf(S[0][0], S[0][1]), fmaxf(S[0][2], S[0][3])),
                       fmaxf(fmaxf(S[1][0], S[1][1]), fmaxf(S[1][2], S[1][3])));
    if (!__all(tmax <= mrun + 8.0f)) {
      tmax = fmaxf(tmax, __shfl_xor(tmax, 16, 64));
      tmax = fmaxf(tmax, __shfl_xor(tmax, 32, 64));
      float mnew = fmaxf(mrun, tmax);
      float sc = __expf(mrun - mnew);
      mrun = mnew;
      rsum *= sc;
      int sb = l & 48;
#pragma unroll
      for (int r = 0; r < 4; ++r) {
        float scO = __shfl(sc, sb | (lq * 4 + r), 64);
#pragma unroll
        for (int c = 0; c < 4; ++c) O[c][r] *= scO;
      }
    }

    // ---- P = exp(S - m) in registers; pi-permuted A-fragment ----
    f32x4 p[2];
#pragma unroll
    for (int c = 0; c < 2; ++c) {
#pragma unroll
      for (int r = 0; r < 4; ++r) p[c][r] = __expf(S[c][r] - mrun);
      rsum += (p[c][0] + p[c][1]) + (p[c][2] + p[c][3]);
    }
    f16x8 pa;
#pragma unroll
    for (int j = 0; j < 4; ++j) {
      pa[j] = (f16)p[0][j];
      pa[4 + j] = (f16)p[1][j];
    }

    // ---- O += P @ V (B-side pi: 2x b64 per dh-block) ----
    const f16* Vcb = &Vb[cur][bb * 2048];
    __builtin_amdgcn_s_setprio(1);
#pragma unroll
    for (int c = 0; c < 4; ++c) {
      int row = c * 16 + lr;
      const f16* vbp = Vcb + row * 32;
      int s4 = row & 3, sub = (lq & 1) * 4, gh = lq >> 1;
      f16x4 v0 = *reinterpret_cast<const f16x4*>(vbp + ((gh ^ s4) * 8 + sub));
      f16x4 v1 = *reinterpret_cast<const f16x4*>(vbp + (((2 + gh) ^ s4) * 8 + sub));
      f16x8 vf;
#pragma unroll
      for (int j = 0; j < 4; ++j) {
        vf[j] = v0[j];
        vf[4 + j] = v1[j];
      }
      O[c] = __builtin_amdgcn_mfma_f32_16x16x32_f16(pa, vf, O[c], 0, 0, 0);
    }
    __builtin_amdgcn_s_setprio(0);
    __builtin_amdgcn_sched_barrier(0);

    // ---- drain stage(t+1) BEFORE barrier (race-free publish) ----
    if (t < 31) {
      asm volatile("s_waitcnt vmcnt(2)" ::: "memory");
      __builtin_amdgcn_sched_barrier(0);
      __builtin_amdgcn_s_barrier();
    }
  };

#pragma unroll 1
  for (int ith = 0; ith < 16; ++ith) {
    body(2 * ith, bA, bB);
    body(2 * ith + 1, bB, bA);
  }

  // ---- deferred sum reduction across the 4 lq replicas ----
  rsum += __shfl_xor(rsum, 16, 64);
  rsum += __shfl_xor(rsum, 32, 64);
  int sb = l & 48;
  float rs[4];
#pragma unroll
  for (int r = 0; r < 4; ++r) rs[r] = __shfl(rsum, sb | (lq * 4 + r), 64);

  // ---- epilogue: ctx[b][q][h*64+dh] f16 (O: q=lq*4+r, dh=c*16+lr) ----
#pragma unroll
  for (int c = 0; c < 4; ++c)
#pragma unroll
    for (int r = 0; r < 4; ++r) {
      float o = O[c][r] / rs[r];
      int row = q0 + qs * 16 + lq * 4 + r;
      ctx[((size_t)bb * 1024 + row) * 1024 + h * 64 + c * 16 + lr] = (f16)o;
    }
}

// ---------------------------------------------------------------------------
extern "C" void kernel_launch(void* const* d_in, const int* in_sizes, int n_in,
                              void* d_out, int out_size, void* d_ws,
                              size_t ws_size, hipStream_t stream) {
  const float* input_ids = (const float*)d_in[0];
  const float* enc = (const float*)d_in[1];
  const float* bias = (const float*)d_in[2];
  const float* Wq = (const float*)d_in[3];
  const float* Wk = (const float*)d_in[4];
  const float* Wv = (const float*)d_in[5];
  const float* Wo = (const float*)d_in[6];

  char* ws = (char*)d_ws;
  const size_t MB = 1024 * 1024;
  f16* Xq  = (f16*)(ws + 0 * MB);   // 8 MB; dead after QKV-proj -> reused as ctx
  f16* Xkv = (f16*)(ws + 8 * MB);   // 8 MB (GEMM A input)
  f16* Wqt = (f16*)(ws + 16 * MB);  // 2 MB each; Wqt|Wkt|Wvt contiguous = [3072][1024]
  f16* Wkt = (f16*)(ws + 18 * MB);
  f16* Wvt = (f16*)(ws + 20 * MB);
  f16* Wot = (f16*)(ws + 22 * MB);
  f16* qbuf = (f16*)(ws + 24 * MB); // 8 MB [bh][s][dh]; kbuf plane follows;
  f16* kbuf = (f16*)(ws + 32 * MB); // plane 2 = vtb [bh][dh][s] (transposed in epi)
  f16* vtb  = (f16*)(ws + 40 * MB);
  f16* ctxb = Xq;   // [4096][1024]

  k_cast2<<<8192, 256, 0, stream>>>(input_ids, enc, Xq, Xkv);
  k_castw_t<<<dim3(16, 16, 4), 256, 0, stream>>>(Wq, Wk, Wv, Wo, Wqt, Wkt, Wvt, Wot);

  // fused Q+K+V projection (V written transposed in epilogue)
  k_gemm_qkv<<<dim3(24, 32), 256, 0, stream>>>(Xq, Xkv, Wqt, qbuf);

  k_attn<<<512, 512, 0, stream>>>(qbuf, kbuf, vtb, bias, ctxb);

  k_gemm_o<<<dim3(8, 64), 256, 0, stream>>>(ctxb, Wot, (float*)d_out, 4096, 1024, 1024);
}

// Round 15
// 137.222 us; speedup vs baseline: 1.1065x; 1.1065x over previous
//
#include <hip/hip_runtime.h>

typedef _Float16 f16;
typedef _Float16 f16x4 __attribute__((ext_vector_type(4)));
typedef _Float16 f16x8 __attribute__((ext_vector_type(8)));
typedef float f32x4 __attribute__((ext_vector_type(4)));

// async global->LDS, 16B per lane; LDS dest = wave-uniform base + lane*16
#define LOADLDS16(gp, lp)                                                     \
  __builtin_amdgcn_global_load_lds(                                           \
      (const __attribute__((address_space(1))) void*)(gp),                    \
      (__attribute__((address_space(3))) void*)(lp), 16, 0, 0)

// ---------------------------------------------------------------------------
// Merged prep: blocks 0-8191 cast activations f32->f16 (float4 vectorized);
// blocks 8192-9215 cast+transpose the 4 weight matrices (64x64 LDS tiles).
// ---------------------------------------------------------------------------
__global__ __launch_bounds__(256) void k_prep(
    const float* __restrict__ xa, const float* __restrict__ xb,
    f16* __restrict__ ya, f16* __restrict__ yb, const float* __restrict__ w0,
    const float* __restrict__ w1, const float* __restrict__ w2,
    const float* __restrict__ w3, f16* __restrict__ o0, f16* __restrict__ o1,
    f16* __restrict__ o2, f16* __restrict__ o3) {
  __shared__ f16 T[64][72];
  const int tid = threadIdx.x;
  const int bid = blockIdx.x;
  if (bid < 8192) {
    int i = bid * 256 + tid;
    const float* x;
    f16* y;
    if (i < 1048576) {
      x = xa; y = ya;
    } else {
      x = xb; y = yb; i -= 1048576;
    }
    float4 v = reinterpret_cast<const float4*>(x)[i];
    f16x4 o;
    o[0] = (f16)v.x; o[1] = (f16)v.y; o[2] = (f16)v.z; o[3] = (f16)v.w;
    reinterpret_cast<f16x4*>(y)[i] = o;
    return;
  }
  const int bid2 = bid - 8192;
  const int z = bid2 >> 8, yb_ = (bid2 >> 4) & 15, xb_ = bid2 & 15;
  const float* W;
  f16* O;
  switch (z) {
    case 0: W = w0; O = o0; break;
    case 1: W = w1; O = o1; break;
    case 2: W = w2; O = o2; break;
    default: W = w3; O = o3; break;
  }
  const int r0 = yb_ * 64, c0 = xb_ * 64;
#pragma unroll
  for (int i = 0; i < 4; ++i) {
    int c = i * 256 + tid;
    int row = c >> 4, col = (c & 15) * 4;
    float4 v = *reinterpret_cast<const float4*>(W + (size_t)(r0 + row) * 1024 + c0 + col);
    T[col + 0][row] = (f16)v.x;
    T[col + 1][row] = (f16)v.y;
    T[col + 2][row] = (f16)v.z;
    T[col + 3][row] = (f16)v.w;
  }
  __syncthreads();
#pragma unroll
  for (int i = 0; i < 2; ++i) {
    int c = i * 256 + tid;
    int cc = c >> 3, ro = (c & 7) * 8;
    f16x8 v;
#pragma unroll
    for (int j = 0; j < 8; ++j) v[j] = T[cc][ro + j];
    *reinterpret_cast<f16x8*>(O + (size_t)(c0 + cc) * 1024 + r0 + ro) = v;
  }
}

// ---------------------------------------------------------------------------
// Fused QKV projection: C[4096, 3072], cols 0-1023 = Xq@Wqt, 1024-2047 =
// Xkv@Wkt, 2048-3071 = Xkv@Wvt. m97 structure: BM=BN=128, BK=64, 4 waves.
// Epilogue: planes 0,1 -> head layout [bh][s][dh]; plane 2 (V) -> TRANSPOSED
// [bh][dh][s] (f16x4 stores over consecutive s) = fused k_vtrans.
// ---------------------------------------------------------------------------
__global__ __launch_bounds__(256) void k_gemm_qkv(const f16* __restrict__ Xq,
                                                  const f16* __restrict__ Xkv,
                                                  const f16* __restrict__ Bt,
                                                  f16* __restrict__ outp) {
  __shared__ f16 As[128 * 64];  // 16 KB
  __shared__ f16 Bs[128 * 64];  // 16 KB
  const int tid = threadIdx.x;
  const int w = tid >> 6, l = tid & 63;
  const int lr = l & 15, lq = l >> 4;
  const int m0 = blockIdx.y * 128, n0 = blockIdx.x * 128;
  const f16* A = (n0 < 1024) ? Xq : Xkv;
  const int wr = (w >> 1) * 64, wc = (w & 1) * 64;
  const int K = 1024;
  f32x4 acc[4][4] = {};
  for (int kt = 0; kt < K; kt += 64) {
#pragma unroll
    for (int i = 0; i < 4; ++i) {
      int c = (i * 4 + w) * 64 + l;
      LOADLDS16(A + (size_t)(m0 + (c >> 3)) * K + kt + (c & 7) * 8,
                As + (size_t)(i * 4 + w) * 512);
      LOADLDS16(Bt + (size_t)(n0 + (c >> 3)) * K + kt + (c & 7) * 8,
                Bs + (size_t)(i * 4 + w) * 512);
    }
    __syncthreads();
#pragma unroll
    for (int kk = 0; kk < 2; ++kk) {
      f16x8 af[4], bf[4];
#pragma unroll
      for (int m = 0; m < 4; ++m)
        af[m] = *reinterpret_cast<const f16x8*>(As + (wr + m * 16 + lr) * 64 + kk * 32 + lq * 8);
#pragma unroll
      for (int n = 0; n < 4; ++n)
        bf[n] = *reinterpret_cast<const f16x8*>(Bs + (wc + n * 16 + lr) * 64 + kk * 32 + lq * 8);
#pragma unroll
      for (int m = 0; m < 4; ++m)
#pragma unroll
        for (int n = 0; n < 4; ++n)
          acc[m][n] = __builtin_amdgcn_mfma_f32_16x16x32_f16(af[m], bf[n], acc[m][n], 0, 0, 0);
    }
    __syncthreads();
  }
  const bool vplane = (n0 >= 2048);
#pragma unroll
  for (int m = 0; m < 4; ++m)
#pragma unroll
    for (int n = 0; n < 4; ++n) {
      int col = n0 + wc + n * 16 + lr;
      int row0 = m0 + wr + m * 16 + lq * 4;
      int b = row0 >> 10, s0 = row0 & 1023;
      int plane = col >> 10, cc = col & 1023;
      int h = cc >> 6, dh = cc & 63;
      if (vplane) {
        f16x4 v4;
#pragma unroll
        for (int r = 0; r < 4; ++r) v4[r] = (f16)acc[m][n][r];
        *reinterpret_cast<f16x4*>(
            outp + (size_t)2 * 4194304 +
            ((size_t)(b * 16 + h)) * 65536 + (size_t)dh * 1024 + s0) = v4;
      } else {
#pragma unroll
        for (int r = 0; r < 4; ++r)
          outp[(size_t)plane * 4194304 +
               (((size_t)(b * 16 + h)) * 1024 + s0 + r) * 64 + dh] =
              (f16)acc[m][n][r];
      }
    }
}

// ---------------------------------------------------------------------------
// Output GEMM: C[M,N] f32 = A[M,K] @ Bt[N,K]^T. BM=64, BN=128 (512 blocks).
// ---------------------------------------------------------------------------
__global__ __launch_bounds__(256) void k_gemm_o(const f16* __restrict__ A,
                                                const f16* __restrict__ Bt,
                                                float* __restrict__ out, int M,
                                                int N, int K) {
  __shared__ f16 As[64 * 64];
  __shared__ f16 Bs[128 * 64];
  const int tid = threadIdx.x;
  const int w = tid >> 6, l = tid & 63;
  const int lr = l & 15, lq = l >> 4;
  const int m0 = blockIdx.y * 64, n0 = blockIdx.x * 128;
  const int wr = (w >> 1) * 32, wc = (w & 1) * 64;
  f32x4 acc[2][4] = {};
  for (int kt = 0; kt < K; kt += 64) {
#pragma unroll
    for (int i = 0; i < 2; ++i) {
      int c = (i * 4 + w) * 64 + l;
      LOADLDS16(A + (size_t)(m0 + (c >> 3)) * K + kt + (c & 7) * 8,
                As + (size_t)(i * 4 + w) * 512);
    }
#pragma unroll
    for (int i = 0; i < 4; ++i) {
      int c = (i * 4 + w) * 64 + l;
      LOADLDS16(Bt + (size_t)(n0 + (c >> 3)) * K + kt + (c & 7) * 8,
                Bs + (size_t)(i * 4 + w) * 512);
    }
    __syncthreads();
#pragma unroll
    for (int kk = 0; kk < 2; ++kk) {
      f16x8 af[2], bf[4];
#pragma unroll
      for (int m = 0; m < 2; ++m)
        af[m] = *reinterpret_cast<const f16x8*>(As + (wr + m * 16 + lr) * 64 + kk * 32 + lq * 8);
#pragma unroll
      for (int n = 0; n < 4; ++n)
        bf[n] = *reinterpret_cast<const f16x8*>(Bs + (wc + n * 16 + lr) * 64 + kk * 32 + lq * 8);
#pragma unroll
      for (int m = 0; m < 2; ++m)
#pragma unroll
        for (int n = 0; n < 4; ++n)
          acc[m][n] = __builtin_amdgcn_mfma_f32_16x16x32_f16(af[m], bf[n], acc[m][n], 0, 0, 0);
    }
    __syncthreads();
  }
#pragma unroll
  for (int m = 0; m < 2; ++m)
#pragma unroll
    for (int n = 0; n < 4; ++n)
#pragma unroll
      for (int r = 0; r < 4; ++r) {
        int row = m0 + wr + m * 16 + lq * 4 + r;
        int col = n0 + wc + n * 16 + lr;
        out[(size_t)row * N + col] = acc[m][n][r];
      }
}

// ---------------------------------------------------------------------------
// Fused flash attention (T5: scores = QK^T + bias, no 1/sqrt scale).
// v13 (best measured: ~65 us): KVBLK=64, 16 periods, race-free counted-vmcnt
// pipeline, co-residency grouping (qt innermost), swapped QK^T, defer-max,
// in-register P (pi-permuted PV fragments), direct-global bias registers.
// ---------------------------------------------------------------------------
__global__ __launch_bounds__(256) void k_attn(const f16* __restrict__ qb,
                                              const f16* __restrict__ kb,
                                              const f16* __restrict__ vtb,
                                              const float* __restrict__ bias,
                                              f16* __restrict__ ctx) {
  const int bid = blockIdx.x;
  const int ord = (bid & 7) * 128 + (bid >> 3);  // XCD-chunked
  const int h = ord >> 6, b = (ord >> 4) & 3, qt = ord & 15;  // qt innermost
  const int bh = b * 16 + h;
  const int q0 = qt * 64;
  const int tid = threadIdx.x, w = tid >> 6, l = tid & 63;
  const int lr = l & 15, lq = l >> 4;

  __shared__ f16 Kb[2][4096];  // [kv=64][dh=64], granule swz g^(row&7)
  __shared__ f16 Vb[2][4096];  // [dh=64][kv=64], granule swz g^(row&7)

  // Q B-fragment: Q[q=w*16+lr][dh=lq*8 (+32)]
  const f16* qp = qb + ((size_t)bh * 1024 + q0 + w * 16 + lr) * 64 + lq * 8;
  f16x8 qf0 = *reinterpret_cast<const f16x8*>(qp);
  f16x8 qf1 = *reinterpret_cast<const f16x8*>(qp + 32);

  f32x4 O[4] = {};
  float mrun = -3.0e38f, rsum = 0.f;  // per-lane; q-row = lr

  const f16* kbase = kb + (size_t)bh * 65536;
  const f16* vbase = vtb + (size_t)bh * 65536;
  const float* bq = bias + ((size_t)h * 1024 + q0 + w * 16 + lr) * 1024 + lq * 4;

  // DMA staging: 512 chunks of 16B per tile; round i, wave w, lane l.
  auto stage = [&](int t, int nxt) {
#pragma unroll
    for (int i = 0; i < 2; ++i) {
      int c = (i * 4 + w) * 64 + l;
      int row = c >> 3, g = (c & 7) ^ (row & 7);
      LOADLDS16(kbase + (size_t)(t * 64 + row) * 64 + g * 8,
                &Kb[nxt][(i * 4 + w) * 512]);
      LOADLDS16(vbase + (size_t)row * 1024 + t * 64 + g * 8,
                &Vb[nxt][(i * 4 + w) * 512]);
    }
  };

  // ---- prologue: stage tile 0 (drained inside body 0 via vmcnt) ----
  stage(0, 0);

#pragma unroll 1
  for (int t = 0; t < 16; ++t) {
    const int cur = t & 1;
    // ---- barrier releases buf^1 (all waves done with body t-1) ----
    __builtin_amdgcn_s_barrier();
    // ---- issue next tile's DMA into buf^1 + this tile's bias loads ----
    if (t < 15) stage(t + 1, cur ^ 1);
    f32x4 bf[4];
#pragma unroll
    for (int c = 0; c < 4; ++c)
      bf[c] = *reinterpret_cast<const f32x4*>(bq + t * 64 + c * 16);
    __builtin_amdgcn_sched_barrier(0);
    // ---- drain ONLY tile t's 4 DMAs (keep t+1's 4 + bias 4 in flight) ----
    if (t < 15) {
      asm volatile("s_waitcnt vmcnt(8)" ::: "memory");
    } else {
      asm volatile("s_waitcnt vmcnt(4)" ::: "memory");
    }
    __builtin_amdgcn_sched_barrier(0);

    // ---- S^T = K Q^T  (rows kv = c*16+lq*4+r, cols q = w*16+lr) ----
    f32x4 S[4] = {};
    __builtin_amdgcn_s_setprio(1);
#pragma unroll
    for (int c = 0; c < 4; ++c) {
      int row = c * 16 + lr;
      const f16* kbp = &Kb[cur][row * 64];
      f16x8 kf0 = *reinterpret_cast<const f16x8*>(kbp + ((lq ^ (row & 7)) * 8));
      f16x8 kf1 = *reinterpret_cast<const f16x8*>(kbp + (((4 + lq) ^ (row & 7)) * 8));
      S[c] = __builtin_amdgcn_mfma_f32_16x16x32_f16(kf0, qf0, S[c], 0, 0, 0);
      S[c] = __builtin_amdgcn_mfma_f32_16x16x32_f16(kf1, qf1, S[c], 0, 0, 0);
    }
    __builtin_amdgcn_s_setprio(0);

    // ---- + bias (registers) ----
#pragma unroll
    for (int c = 0; c < 4; ++c)
#pragma unroll
      for (int r = 0; r < 4; ++r) S[c][r] += bf[c][r];

    // ---- defer-max (T13): per-lane bound check; rare reduce+rescale ----
    float tmax = fmaxf(
        fmaxf(fmaxf(fmaxf(S[0][0], S[0][1]), fmaxf(S[0][2], S[0][3])),
              fmaxf(fmaxf(S[1][0], S[1][1]), fmaxf(S[1][2], S[1][3]))),
        fmaxf(fmaxf(fmaxf(S[2][0], S[2][1]), fmaxf(S[2][2], S[2][3])),
              fmaxf(fmaxf(S[3][0], S[3][1]), fmaxf(S[3][2], S[3][3]))));
    if (!__all(tmax <= mrun + 8.0f)) {
      tmax = fmaxf(tmax, __shfl_xor(tmax, 16, 64));
      tmax = fmaxf(tmax, __shfl_xor(tmax, 32, 64));
      float mnew = fmaxf(mrun, tmax);
      float sc = __expf(mrun - mnew);
      mrun = mnew;
      rsum *= sc;
      int sb = l & 48;
#pragma unroll
      for (int r = 0; r < 4; ++r) {
        float scO = __shfl(sc, sb | (lq * 4 + r), 64);
#pragma unroll
        for (int c = 0; c < 4; ++c) O[c][r] *= scO;
      }
    }

    // ---- P = exp(S - m) in REGISTERS (pi-permuted A-fragments) ----
    f32x4 p[4];
#pragma unroll
    for (int c = 0; c < 4; ++c) {
#pragma unroll
      for (int r = 0; r < 4; ++r) p[c][r] = __expf(S[c][r] - mrun);
      rsum += (p[c][0] + p[c][1]) + (p[c][2] + p[c][3]);
    }
    f16x8 pa0, pa1;
#pragma unroll
    for (int j = 0; j < 4; ++j) {
      pa0[j] = (f16)p[0][j];
      pa0[4 + j] = (f16)p[1][j];
      pa1[j] = (f16)p[2][j];
      pa1[4 + j] = (f16)p[3][j];
    }

    // ---- O += P @ V (B-side pi: 4x b64 per dh-block) ----
    __builtin_amdgcn_s_setprio(1);
#pragma unroll
    for (int c = 0; c < 4; ++c) {
      int row = c * 16 + lr;
      const f16* vbp = &Vb[cur][row * 64];
      int s8 = row & 7, sub = (lq & 1) * 4, gh = lq >> 1;
      f16x4 v0 = *reinterpret_cast<const f16x4*>(vbp + ((gh ^ s8) * 8 + sub));
      f16x4 v1 = *reinterpret_cast<const f16x4*>(vbp + (((2 + gh) ^ s8) * 8 + sub));
      f16x4 v2 = *reinterpret_cast<const f16x4*>(vbp + (((4 + gh) ^ s8) * 8 + sub));
      f16x4 v3 = *reinterpret_cast<const f16x4*>(vbp + (((6 + gh) ^ s8) * 8 + sub));
      f16x8 vf0, vf1;
#pragma unroll
      for (int j = 0; j < 4; ++j) {
        vf0[j] = v0[j];
        vf0[4 + j] = v1[j];
        vf1[j] = v2[j];
        vf1[4 + j] = v3[j];
      }
      O[c] = __builtin_amdgcn_mfma_f32_16x16x32_f16(pa0, vf0, O[c], 0, 0, 0);
      O[c] = __builtin_amdgcn_mfma_f32_16x16x32_f16(pa1, vf1, O[c], 0, 0, 0);
    }
    __builtin_amdgcn_s_setprio(0);
    // pin the whole body between its barriers
    __builtin_amdgcn_sched_barrier(0);
  }

  // ---- deferred sum reduction across the 4 lq replicas ----
  rsum += __shfl_xor(rsum, 16, 64);
  rsum += __shfl_xor(rsum, 32, 64);
  int sb = l & 48;
  float rs[4];
#pragma unroll
  for (int r = 0; r < 4; ++r) rs[r] = __shfl(rsum, sb | (lq * 4 + r), 64);

  // ---- epilogue: ctx[b][q][h*64+dh] f16 (O: q=lq*4+r, dh=c*16+lr) ----
#pragma unroll
  for (int c = 0; c < 4; ++c)
#pragma unroll
    for (int r = 0; r < 4; ++r) {
      float o = O[c][r] / rs[r];
      int row = q0 + w * 16 + lq * 4 + r;
      ctx[((size_t)b * 1024 + row) * 1024 + h * 64 + c * 16 + lr] = (f16)o;
    }
}

// ---------------------------------------------------------------------------
extern "C" void kernel_launch(void* const* d_in, const int* in_sizes, int n_in,
                              void* d_out, int out_size, void* d_ws,
                              size_t ws_size, hipStream_t stream) {
  const float* input_ids = (const float*)d_in[0];
  const float* enc = (const float*)d_in[1];
  const float* bias = (const float*)d_in[2];
  const float* Wq = (const float*)d_in[3];
  const float* Wk = (const float*)d_in[4];
  const float* Wv = (const float*)d_in[5];
  const float* Wo = (const float*)d_in[6];

  char* ws = (char*)d_ws;
  const size_t MB = 1024 * 1024;
  f16* Xq  = (f16*)(ws + 0 * MB);   // 8 MB; dead after QKV-proj -> reused as ctx
  f16* Xkv = (f16*)(ws + 8 * MB);   // 8 MB (GEMM A input)
  f16* Wqt = (f16*)(ws + 16 * MB);  // 2 MB each; Wqt|Wkt|Wvt contiguous = [3072][1024]
  f16* Wkt = (f16*)(ws + 18 * MB);
  f16* Wvt = (f16*)(ws + 20 * MB);
  f16* Wot = (f16*)(ws + 22 * MB);
  f16* qbuf = (f16*)(ws + 24 * MB); // 8 MB [bh][s][dh]; kbuf plane follows;
  f16* kbuf = (f16*)(ws + 32 * MB); // plane 2 = vtb [bh][dh][s] (transposed in epi)
  f16* vtb  = (f16*)(ws + 40 * MB);
  f16* ctxb = Xq;   // [4096][1024]

  // merged cast + weight-transpose prep (one launch)
  k_prep<<<9216, 256, 0, stream>>>(input_ids, enc, Xq, Xkv, Wq, Wk, Wv, Wo,
                                   Wqt, Wkt, Wvt, Wot);

  // fused Q+K+V projection (V written transposed in epilogue)
  k_gemm_qkv<<<dim3(24, 32), 256, 0, stream>>>(Xq, Xkv, Wqt, qbuf);

  k_attn<<<1024, 256, 0, stream>>>(qbuf, kbuf, vtb, bias, ctxb);

  k_gemm_o<<<dim3(8, 64), 256, 0, stream>>>(ctxb, Wot, (float*)d_out, 4096, 1024, 1024);
}